// Round 5
// baseline (43.750 us; speedup 1.0000x reference)
//
#include <hip/hip_runtime.h>
#include <math.h>

// Rodrigues rotation: R rotates unit(vec1) onto unit(vec2), per (B,N) element.
// B*N = 2,097,152 elements; in: 2 x (elem,3) f32, out: (elem,3,3) f32.
// Memory-bound: ~126 MB total traffic -> floor ~20 us @ 6.3 TB/s copy ceiling.
//
// R4 = R3 with the nontemporal-store type fixed (clang ext_vector float4).
//   loads:  direct stride-3 float4 per thread (no LDS, no barrier; L1 reuses
//           each 128B line across the wave's 3-instr window)
//   stores: LDS-staged transpose (9x ds_write_b128 stride-9-f4, one barrier,
//           9 linear coalesced nontemporal float4 passes)
//   math:   approx rcp/rsq; wave-uniform __any(s2==0) guard branches over the
//           180-degree/identity fixup (never taken for random-normal data,
//           still correct when taken; depends only on input values).

#define TPB 128
#define EPT 4
#define EPB (TPB * EPT)            // 512 elements per block
#define OUTF4 (9 * EPB / 4)        // 1152 float4 of output per block

typedef float v4f __attribute__((ext_vector_type(4)));

__device__ __forceinline__ void rot_main(const float* __restrict__ va,
                                         const float* __restrict__ vb,
                                         float* __restrict__ R,
                                         float* __restrict__ s2o,
                                         float* __restrict__ co)
{
    const float v1x = va[0], v1y = va[1], v1z = va[2];
    const float v2x = vb[0], v2y = vb[1], v2z = vb[2];
    const float rn1 = __builtin_amdgcn_rsqf(v1x * v1x + v1y * v1y + v1z * v1z);
    const float rn2 = __builtin_amdgcn_rsqf(v2x * v2x + v2y * v2y + v2z * v2z);
    const float ax = v1x * rn1, ay = v1y * rn1, az = v1z * rn1;
    const float bx = v2x * rn2, by = v2y * rn2, bz = v2z * rn2;

    const float vx = ay * bz - az * by;
    const float vy = az * bx - ax * bz;
    const float vz = ax * by - ay * bx;
    const float c  = ax * bx + ay * by + az * bz;
    const float s2 = vx * vx + vy * vy + vz * vz;

    // s < 1e-30 (f64 in ref)  <=>  s2 == 0 in f32
    const bool s_zero = (s2 == 0.0f);
    const float f = (1.0f - c) * (s_zero ? 1.0f : __builtin_amdgcn_rcpf(s2));

    // R = I + K + (v v^T - s2 I) * f   (K^2 == v v^T - |v|^2 I exactly)
    R[0] = 1.0f + (vx * vx - s2) * f;
    R[1] = -vz  + (vx * vy) * f;
    R[2] =  vy  + (vx * vz) * f;
    R[3] =  vz  + (vy * vx) * f;
    R[4] = 1.0f + (vy * vy - s2) * f;
    R[5] = -vx  + (vy * vz) * f;
    R[6] = -vy  + (vz * vx) * f;
    R[7] =  vx  + (vz * vy) * f;
    R[8] = 1.0f + (vz * vz - s2) * f;

    *s2o = s2;
    *co  = c;
}

// Rare-path fixup: identity / 180-degree cases (recomputes a from raw input).
__device__ __noinline__ void rot_fixup(const float* __restrict__ va,
                                       float s2, float c, float* __restrict__ R)
{
    const bool s_zero = (s2 == 0.0f);
    if (!s_zero) return;

    const float v1x = va[0], v1y = va[1], v1z = va[2];
    const float rn1 = __builtin_amdgcn_rsqf(v1x * v1x + v1y * v1y + v1z * v1z);
    const float ax = v1x * rn1, ay = v1y * rn1, az = v1z * rn1;

    const bool close = (fabsf(ax - 1.0f) <= (1e-8f + 1e-5f)) &&
                       (fabsf(ay) <= 1e-8f) &&
                       (fabsf(az) <= 1e-8f);
    const float exv = close ? 0.0f : 1.0f;   // axis = close ? e2 : e1
    const float eyv = close ? 1.0f : 0.0f;
    float px = -az * eyv;
    float py =  az * exv;
    float pz =  ax * eyv - ay * exv;
    const float pq0 = px * px + py * py + pz * pz;
    const float rpn = (pq0 == 0.0f) ? 1.0f : __builtin_amdgcn_rsqf(pq0);
    px *= rpn; py *= rpn; pz *= rpn;
    const float pq = px * px + py * py + pz * pz;

    if (c > 0.0f) {
        R[0] = 1.0f; R[1] = 0.0f; R[2] = 0.0f;
        R[3] = 0.0f; R[4] = 1.0f; R[5] = 0.0f;
        R[6] = 0.0f; R[7] = 0.0f; R[8] = 1.0f;
    } else if (c < 0.0f) {
        R[0] = 1.0f + 2.0f * (px * px - pq);
        R[1] = 2.0f * (px * py);
        R[2] = 2.0f * (px * pz);
        R[3] = R[1];
        R[4] = 1.0f + 2.0f * (py * py - pq);
        R[5] = 2.0f * (py * pz);
        R[6] = R[2];
        R[7] = R[5];
        R[8] = 1.0f + 2.0f * (pz * pz - pq);
    }
}

__global__ __launch_bounds__(TPB, 4)
void rodrigues_direct(const float4* __restrict__ v1,
                      const float4* __restrict__ v2,
                      float4* __restrict__ out)
{
    __shared__ float4 lds[OUTF4];                 // 18 KB -> 8 blocks/CU

    const int tid = threadIdx.x;
    const long gt = (long)blockIdx.x * TPB + tid; // global thread index

    // ---- direct loads: 3x float4 per input, stride-3-f4 across lanes ----
    const float4 A0 = v1[3 * gt + 0], A1 = v1[3 * gt + 1], A2 = v1[3 * gt + 2];
    const float4 B0 = v2[3 * gt + 0], B1 = v2[3 * gt + 1], B2 = v2[3 * gt + 2];

    const float va[12] = {A0.x, A0.y, A0.z, A0.w, A1.x, A1.y, A1.z, A1.w,
                          A2.x, A2.y, A2.z, A2.w};
    const float vb[12] = {B0.x, B0.y, B0.z, B0.w, B1.x, B1.y, B1.z, B1.w,
                          B2.x, B2.y, B2.z, B2.w};

    float R[36], s2e[4], ce[4];
#pragma unroll
    for (int e = 0; e < 4; ++e)
        rot_main(&va[3 * e], &vb[3 * e], &R[9 * e], &s2e[e], &ce[e]);

    // Wave-uniform rare-path guard: for random data no lane ever takes it.
    const bool any_spec = (s2e[0] == 0.0f) | (s2e[1] == 0.0f) |
                          (s2e[2] == 0.0f) | (s2e[3] == 0.0f);
    if (__any(any_spec)) {
#pragma unroll
        for (int e = 0; e < 4; ++e)
            rot_fixup(&va[3 * e], s2e[e], ce[e], &R[9 * e]);
    }

    // ---- regs -> LDS: 9x ds_write_b128 at stride 9 f4 ----
#pragma unroll
    for (int k = 0; k < 9; ++k)
        lds[9 * tid + k] = make_float4(R[4 * k + 0], R[4 * k + 1],
                                       R[4 * k + 2], R[4 * k + 3]);
    __syncthreads();

    // ---- LDS -> global: 9 linear coalesced nontemporal float4 passes ----
    const v4f* lsrc = (const v4f*)lds;
    v4f* go = (v4f*)(out + (long)blockIdx.x * OUTF4);
#pragma unroll
    for (int p = 0; p < 9; ++p)
        __builtin_nontemporal_store(lsrc[p * TPB + tid], &go[p * TPB + tid]);
}

// Scalar tail for n % EPB leftovers (not launched for this shape).
__global__ __launch_bounds__(64)
void rodrigues1_kernel(const float* __restrict__ v1,
                       const float* __restrict__ v2,
                       float* __restrict__ out, int start, int n)
{
    const int i = start + blockIdx.x * blockDim.x + threadIdx.x;
    if (i >= n) return;
    float R[9], s2, c;
    float a3[3] = {v1[3 * i + 0], v1[3 * i + 1], v1[3 * i + 2]};
    float b3[3] = {v2[3 * i + 0], v2[3 * i + 1], v2[3 * i + 2]};
    rot_main(a3, b3, R, &s2, &c);
    rot_fixup(a3, s2, c, R);
#pragma unroll
    for (int k = 0; k < 9; ++k) out[9 * i + k] = R[k];
}

extern "C" void kernel_launch(void* const* d_in, const int* in_sizes, int n_in,
                              void* d_out, int out_size, void* d_ws, size_t ws_size,
                              hipStream_t stream)
{
    const float* v1 = (const float*)d_in[0];
    const float* v2 = (const float*)d_in[1];
    const int n = in_sizes[0] / 3;               // B*N elements (2,097,152)

    const int nfull = n / EPB;                   // full 512-element blocks
    if (nfull > 0) {
        rodrigues_direct<<<nfull, TPB, 0, stream>>>(
            (const float4*)v1, (const float4*)v2, (float4*)d_out);
    }
    const int rem = n - nfull * EPB;
    if (rem > 0) {
        rodrigues1_kernel<<<(rem + 63) / 64, 64, 0, stream>>>(
            v1, v2, (float*)d_out, nfull * EPB, n);
    }
}